// Round 14
// baseline (343.523 us; speedup 1.0000x reference)
//
#include <hip/hip_runtime.h>
#include <hip/hip_bf16.h>
#include <stdint.h>

#define L_SEQ 8192
#define S_SEQ 512
#define DIM   2048
#define CTX   4096
#define NH    16
#define HD    128

typedef __bf16 bf16_t;
typedef bf16_t bf16x8 __attribute__((ext_vector_type(8)));
typedef float  f32x4_t __attribute__((ext_vector_type(4)));
typedef float  f32x16_t __attribute__((ext_vector_type(16)));

__device__ __forceinline__ ushort f2b(float f) {
  bf16_t h = (bf16_t)f;
  return __builtin_bit_cast(ushort, h);
}
__device__ __forceinline__ uint32_t pk2(float a, float b) {
  return (uint32_t)f2b(a) | ((uint32_t)f2b(b) << 16);
}
__device__ __forceinline__ float b2f(ushort u) {
  union { uint32_t u; float f; } v; v.u = ((uint32_t)u) << 16;
  return v.f;
}
__device__ __forceinline__ void gll16(const ushort* g, ushort* l) {
  __builtin_amdgcn_global_load_lds((const __attribute__((address_space(1))) void*)g,
                                   (__attribute__((address_space(3))) void*)l, 16, 0, 0);
}
#define SBAR() __builtin_amdgcn_sched_barrier(0)

// ============ fused preprocessing: x/ctx casts + 4 weight transposes + G ============
__global__ __launch_bounds__(256) void k_prep(const float* __restrict__ x,
                                              const float* __restrict__ ctx,
                                              const float* __restrict__ Wq,
                                              const float* __restrict__ Wk,
                                              const float* __restrict__ Wv,
                                              const float* __restrict__ Wo,
                                              const float* __restrict__ gq,
                                              const float* __restrict__ gk,
                                              ushort* __restrict__ xb,
                                              ushort* __restrict__ ctxb,
                                              ushort* __restrict__ wqt,
                                              ushort* __restrict__ wkt,
                                              ushort* __restrict__ wvt,
                                              ushort* __restrict__ wot,
                                              float* __restrict__ g2) {
  const int b = blockIdx.x;
  const int tid = threadIdx.x;
  if (b == 33792) {  // G = gq*gk/sqrt(HD)
    const int d = tid * 8;
#pragma unroll
    for (int j = 0; j < 8; j++) g2[d + j] = gq[d + j] * gk[d + j] * 0.08838834764831843f;
    return;
  }
  if (b < 9216) {  // elementwise casts
    const float* src; ushort* dst; size_t i;
    if (b < 8192) { src = x;   dst = xb;   i = ((size_t)b * 256 + tid) * 8; }
    else          { src = ctx; dst = ctxb; i = ((size_t)(b - 8192) * 256 + tid) * 8; }
    float4 a = *(const float4*)(src + i);
    float4 c = *(const float4*)(src + i + 4);
    uint4 r;
    r.x = pk2(a.x, a.y); r.y = pk2(a.z, a.w);
    r.z = pk2(c.x, c.y); r.w = pk2(c.z, c.w);
    *(uint4*)(dst + i) = r;
    return;
  }
  // transpose + cast fp32 [K][2048] -> bf16 [2048][K]
  __shared__ float t[32][33];
  const float* src; ushort* dst; int K, ti;
  if (b < 13312)      { src = Wq; dst = wqt; K = DIM; ti = b - 9216; }
  else if (b < 21504) { src = Wk; dst = wkt; K = CTX; ti = b - 13312; }
  else if (b < 29696) { src = Wv; dst = wvt; K = CTX; ti = b - 21504; }
  else                { src = Wo; dst = wot; K = DIM; ti = b - 29696; }
  const int n0 = (ti & 63) * 32, k0 = (ti >> 6) * 32;
  const int tx = tid & 31, ty = tid >> 5;
#pragma unroll
  for (int i = 0; i < 4; i++)
    t[ty + 8 * i][tx] = src[(size_t)(k0 + ty + 8 * i) * DIM + n0 + tx];
  __syncthreads();
#pragma unroll
  for (int i = 0; i < 4; i++)
    dst[(size_t)(n0 + ty + 8 * i) * K + k0 + tx] = f2b(t[tx][ty + 8 * i]);
}

// ============ K rms-normalize (512 rows) ============
__global__ __launch_bounds__(256) void k_knorm(const ushort* __restrict__ kraw,
                                               ushort* __restrict__ kb) {
  const int row = blockIdx.x, tid = threadIdx.x;
  uint4 v = *(const uint4*)(kraw + (size_t)row * DIM + tid * 8);
  const uint32_t* vu = (const uint32_t*)&v;
  float f[8];
#pragma unroll
  for (int i = 0; i < 4; i++) {
    f[2 * i]     = b2f((ushort)(vu[i] & 0xffffu));
    f[2 * i + 1] = b2f((ushort)(vu[i] >> 16));
  }
  float s = 0.f;
#pragma unroll
  for (int i = 0; i < 8; i++) s += f[i] * f[i];
#pragma unroll
  for (int off = 32; off; off >>= 1) s += __shfl_down(s, off);
  __shared__ float wsum[4];
  __shared__ float rtot;
  if ((tid & 63) == 0) wsum[tid >> 6] = s;
  __syncthreads();
  if (tid == 0)
    rtot = rsqrtf((wsum[0] + wsum[1] + wsum[2] + wsum[3]) * (1.0f / DIM) + 1e-6f);
  __syncthreads();
  const float rms = rtot;
  ushort r[8];
#pragma unroll
  for (int i = 0; i < 8; i++) r[i] = f2b(f[i] * rms);
  *(uint4*)(kb + (size_t)row * DIM + tid * 8) = *(uint4*)r;
}

// ======================= 256x256 8-wave 4-phase GEMM (round-12 schedule) ==========
template <int OUT_MODE>
__global__ __launch_bounds__(512, 2) void k_gemm256(const ushort* __restrict__ A,
                                                    const ushort* __restrict__ Bt,
                                                    const float* __restrict__ bias,
                                                    void* __restrict__ outp,
                                                    float* __restrict__ qpart,
                                                    int M, int N, int K) {
  __shared__ __align__(16) ushort lds[65536];  // 128 KB
  const int tid = threadIdx.x;
  const int l = tid & 63, wid = tid >> 6;
  const int wm = wid >> 2, wn = wid & 3;
  const int lr = l & 15, lq = l >> 4;

  const int nwg = gridDim.x * gridDim.y;
  const int bid = blockIdx.y * gridDim.x + blockIdx.x;
  const int swz = (bid & 7) * (nwg >> 3) + (bid >> 3);
  const int m0 = (swz / gridDim.x) * 256, n0 = (swz % gridDim.x) * 256;

  f32x4_t acc[8][4];
#pragma unroll
  for (int i = 0; i < 8; i++)
#pragma unroll
    for (int j = 0; j < 4; j++) acc[i][j] = f32x4_t{0.f, 0.f, 0.f, 0.f};

  const int srow = l >> 3;
  const int schunk = ((l & 7) ^ (srow & 7)) * 8;
  auto stage = [&](int buf, int tile, int mat, int h) {
    const ushort* gp = mat ? Bt : A;
    const int rn0 = mat ? n0 : m0;
    const size_t r0 = (size_t)(rn0 + h * 128 + wid * 8 + srow);
    const ushort* g0 = gp + r0 * K + tile * 64 + schunk;
    ushort* l0 = &lds[buf * 32768 + mat * 16384 + (h * 128 + wid * 8) * 64];
    gll16(g0, l0);
    gll16(g0 + (size_t)64 * K, l0 + 64 * 64);
  };

  auto rdA = [&](int buf, int mf, int ks) -> bf16x8 {
    const int R = wm * 128 + mf * 16 + lr;
    return *(const bf16x8*)(&lds[buf * 32768 + R * 64 + (((ks * 4 + lq) ^ (R & 7)) * 8)]);
  };
  auto rdB = [&](int buf, int nf, int ks) -> bf16x8 {
    const int R = wn * 64 + nf * 16 + lr;
    return *(const bf16x8*)(&lds[buf * 32768 + 16384 + R * 64 + (((ks * 4 + lq) ^ (R & 7)) * 8)]);
  };

  const int NT = K >> 6;
  stage(0, 0, 0, 0); stage(0, 0, 0, 1); stage(0, 0, 1, 0); stage(0, 0, 1, 1);

  bf16x8 a[4][2], a2[4][2], b[2][2], b2[2][2];
  for (int kt = 0; kt < NT; kt++) {
    const int cur = kt & 1, nxt = cur ^ 1;
    const bool pf = (kt + 1 < NT);
    if (pf) { stage(nxt, kt + 1, 0, 0); asm volatile("s_waitcnt vmcnt(2)" ::: "memory"); }
    else    { asm volatile("s_waitcnt vmcnt(0)" ::: "memory"); }
    SBAR();
    __builtin_amdgcn_s_barrier();
    SBAR();
#pragma unroll
    for (int mf = 0; mf < 4; mf++) { a[mf][0] = rdA(cur, mf, 0); a[mf][1] = rdA(cur, mf, 1); }
#pragma unroll
    for (int nf = 0; nf < 2; nf++) { b[nf][0] = rdB(cur, nf, 0); b[nf][1] = rdB(cur, nf, 1); }
    __builtin_amdgcn_s_setprio(1);
#pragma unroll
    for (int mf = 0; mf < 4; mf++)
#pragma unroll
      for (int nf = 0; nf < 2; nf++) {
        acc[mf][nf] = __builtin_amdgcn_mfma_f32_16x16x32_bf16(a[mf][0], b[nf][0], acc[mf][nf], 0, 0, 0);
        acc[mf][nf] = __builtin_amdgcn_mfma_f32_16x16x32_bf16(a[mf][1], b[nf][1], acc[mf][nf], 0, 0, 0);
      }
    __builtin_amdgcn_s_setprio(0);
    SBAR();
    __builtin_amdgcn_s_barrier();
    SBAR();
#pragma unroll
    for (int mf = 0; mf < 4; mf++) { a2[mf][0] = rdA(cur, mf + 4, 0); a2[mf][1] = rdA(cur, mf + 4, 1); }
    if (pf) stage(nxt, kt + 1, 0, 1);
    SBAR();
    __builtin_amdgcn_s_barrier();
    SBAR();
    __builtin_amdgcn_s_setprio(1);
#pragma unroll
    for (int mf = 0; mf < 4; mf++)
#pragma unroll
      for (int nf = 0; nf < 2; nf++) {
        acc[mf + 4][nf] = __builtin_amdgcn_mfma_f32_16x16x32_bf16(a2[mf][0], b[nf][0], acc[mf + 4][nf], 0, 0, 0);
        acc[mf + 4][nf] = __builtin_amdgcn_mfma_f32_16x16x32_bf16(a2[mf][1], b[nf][1], acc[mf + 4][nf], 0, 0, 0);
      }
    __builtin_amdgcn_s_setprio(0);
    SBAR();
    __builtin_amdgcn_s_barrier();
    SBAR();
#pragma unroll
    for (int nf = 0; nf < 2; nf++) { b2[nf][0] = rdB(cur, nf + 2, 0); b2[nf][1] = rdB(cur, nf + 2, 1); }
    if (pf) stage(nxt, kt + 1, 1, 0);
    SBAR();
    __builtin_amdgcn_s_barrier();
    SBAR();
    __builtin_amdgcn_s_setprio(1);
#pragma unroll
    for (int mf = 0; mf < 4; mf++)
#pragma unroll
      for (int nf = 0; nf < 2; nf++) {
        acc[mf + 4][nf + 2] = __builtin_amdgcn_mfma_f32_16x16x32_bf16(a2[mf][0], b2[nf][0], acc[mf + 4][nf + 2], 0, 0, 0);
        acc[mf + 4][nf + 2] = __builtin_amdgcn_mfma_f32_16x16x32_bf16(a2[mf][1], b2[nf][1], acc[mf + 4][nf + 2], 0, 0, 0);
      }
    __builtin_amdgcn_s_setprio(0);
    SBAR();
    __builtin_amdgcn_s_barrier();
    SBAR();
#pragma unroll
    for (int mf = 0; mf < 4; mf++) { a[mf][0] = rdA(cur, mf, 0); a[mf][1] = rdA(cur, mf, 1); }
    if (pf) stage(nxt, kt + 1, 1, 1);
    SBAR();
    __builtin_amdgcn_s_barrier();
    SBAR();
    __builtin_amdgcn_s_setprio(1);
#pragma unroll
    for (int mf = 0; mf < 4; mf++)
#pragma unroll
      for (int nf = 0; nf < 2; nf++) {
        acc[mf][nf + 2] = __builtin_amdgcn_mfma_f32_16x16x32_bf16(a[mf][0], b2[nf][0], acc[mf][nf + 2], 0, 0, 0);
        acc[mf][nf + 2] = __builtin_amdgcn_mfma_f32_16x16x32_bf16(a[mf][1], b2[nf][1], acc[mf][nf + 2], 0, 0, 0);
      }
    __builtin_amdgcn_s_setprio(0);
    SBAR();
    __builtin_amdgcn_s_barrier();
    SBAR();
  }

  // ---- epilogue ----
  float bvs[4];
#pragma unroll
  for (int nf = 0; nf < 4; nf++) bvs[nf] = bias[n0 + wn * 64 + nf * 16 + lr];
#pragma unroll
  for (int nf = 0; nf < 4; nf++) {
    const int col = n0 + wn * 64 + nf * 16 + lr;
#pragma unroll
    for (int mf = 0; mf < 8; mf++) {
#pragma unroll
      for (int r = 0; r < 4; r++) {
        const int row = m0 + wm * 128 + mf * 16 + lq * 4 + r;
        const float v = acc[mf][nf][r] + bvs[nf];
        if constexpr (OUT_MODE == 0)
          ((float*)outp)[(size_t)row * N + col] = v;
        else
          ((ushort*)outp)[(size_t)row * N + col] = f2b(v);
      }
    }
  }
  if constexpr (OUT_MODE == 1) {
    const int slot = (n0 >> 8) * 4 + wn;
#pragma unroll
    for (int mf = 0; mf < 8; mf++) {
#pragma unroll
      for (int r = 0; r < 4; r++) {
        float s = 0.f;
#pragma unroll
        for (int nf = 0; nf < 4; nf++) {
          const float v = acc[mf][nf][r] + bvs[nf];
          s += v * v;
        }
        s += __shfl_xor(s, 1); s += __shfl_xor(s, 2);
        s += __shfl_xor(s, 4); s += __shfl_xor(s, 8);
        if (lr == 0)
          qpart[(size_t)(m0 + wm * 128 + mf * 16 + lq * 4 + r) * 32 + slot] = s;
      }
    }
  }
}

// ============ KV projection GEMM: depth-6 pipeline (5-tile load lead) ============
__global__ __launch_bounds__(256) void k_gemmkv(const ushort* __restrict__ A,
                                                const ushort* __restrict__ Bt,
                                                const float* __restrict__ biasK,
                                                const float* __restrict__ biasV,
                                                ushort* __restrict__ outK,
                                                ushort* __restrict__ outVt) {
  __shared__ __align__(16) ushort As[6][128 * 32];  // 48 KB
  __shared__ __align__(16) ushort Bs[6][64 * 32];   // 24 KB
  const int tid = threadIdx.x;
  const int l = tid & 63, wid = tid >> 6;
  const int wr = wid >> 1, wc = wid & 1;
  const int lr = l & 15, lq = l >> 4;
  const int K = CTX, M = S_SEQ;

  const int bid = blockIdx.x;                 // grid = 256
  const int swz = (bid & 7) * 32 + (bid >> 3);
  const int n0 = (swz >> 2) * 64, m0 = (swz & 3) * 128;

  f32x4_t acc[4][2];
#pragma unroll
  for (int i = 0; i < 4; i++)
#pragma unroll
    for (int j = 0; j < 2; j++) acc[i][j] = f32x4_t{0.f, 0.f, 0.f, 0.f};

  const int srow = l >> 2;
  const int schunk = ((l & 3) ^ ((srow >> 1) & 3)) * 8;
  const ushort* gA = A  + (size_t)(m0 + srow) * K + schunk;
  const ushort* gB = Bt + (size_t)(n0 + wid * 16 + srow) * K + schunk;

  auto stage = [&](int buf, int kt) {
    const int ko = kt * 32;
    gll16(gA + (size_t)(wid * 16) * K + ko,      &As[buf][(wid * 16) * 32]);
    gll16(gA + (size_t)(64 + wid * 16) * K + ko, &As[buf][(64 + wid * 16) * 32]);
    gll16(gB + ko,                               &Bs[buf][(wid * 16) * 32]);
  };
  auto rdA = [&](int buf, int mi) -> bf16x8 {
    const int R = wr * 64 + mi * 16 + lr;
    return *(const bf16x8*)(&As[buf][R * 32 + ((lq ^ ((R >> 1) & 3)) * 8)]);
  };
  auto rdB = [&](int buf, int ni) -> bf16x8 {
    const int R = wc * 32 + ni * 16 + lr;
    return *(const bf16x8*)(&Bs[buf][R * 32 + ((lq ^ ((R >> 1) & 3)) * 8)]);
  };

  const int NT = K >> 5;  // 128
  stage(0, 0); stage(1, 1); stage(2, 2); stage(3, 3); stage(4, 4);
  int cur = 0;
  for (int t = 0; t < NT; t++) {
    // stage tile t+5 into the PREVIOUS tile's buffer (reads done by iter t-1's
    // end barrier). Steady-state 18 loads outstanding -> vmcnt(15) drains tile t.
    if (t + 5 < NT) {
      const int prv = (cur == 0) ? 5 : cur - 1;
      stage(prv, t + 5);
      asm volatile("s_waitcnt vmcnt(15)" ::: "memory");
    }
    else if (t + 4 < NT) { asm volatile("s_waitcnt vmcnt(12)" ::: "memory"); }
    else if (t + 3 < NT) { asm volatile("s_waitcnt vmcnt(9)" ::: "memory"); }
    else if (t + 2 < NT) { asm volatile("s_waitcnt vmcnt(6)" ::: "memory"); }
    else if (t + 1 < NT) { asm volatile("s_waitcnt vmcnt(3)" ::: "memory"); }
    else                 { asm volatile("s_waitcnt vmcnt(0)" ::: "memory"); }
    SBAR();
    __builtin_amdgcn_s_barrier();
    SBAR();

    bf16x8 af[4], bfr[2];
#pragma unroll
    for (int mi = 0; mi < 4; mi++) af[mi] = rdA(cur, mi);
#pragma unroll
    for (int ni = 0; ni < 2; ni++) bfr[ni] = rdB(cur, ni);
    __builtin_amdgcn_s_setprio(1);
#pragma unroll
    for (int mi = 0; mi < 4; mi++)
#pragma unroll
      for (int ni = 0; ni < 2; ni++)
        acc[mi][ni] = __builtin_amdgcn_mfma_f32_16x16x32_bf16(af[mi], bfr[ni], acc[mi][ni], 0, 0, 0);
    __builtin_amdgcn_s_setprio(0);
    SBAR();
    __builtin_amdgcn_s_barrier();
    SBAR();
    cur = (cur == 5) ? 0 : cur + 1;
  }

  if (n0 < DIM) {
#pragma unroll
    for (int mi = 0; mi < 4; mi++) {
#pragma unroll
      for (int ni = 0; ni < 2; ni++) {
        const int col = n0 + wc * 32 + ni * 16 + lr;
        const float bv = biasK[col];
#pragma unroll
        for (int r = 0; r < 4; r++) {
          const int row = m0 + wr * 64 + mi * 16 + lq * 4 + r;
          outK[(size_t)row * DIM + col] = f2b(acc[mi][ni][r] + bv);
        }
      }
    }
  } else {
    // V block: transpose through LDS for coalesced V^T stores
    ushort* ldst = &As[0][0];
    __syncthreads();
#pragma unroll
    for (int mi = 0; mi < 4; mi++) {
#pragma unroll
      for (int ni = 0; ni < 2; ni++) {
        const int ccol = wc * 32 + ni * 16 + lr;
        const float bv = biasV[n0 - DIM + ccol];
#pragma unroll
        for (int r = 0; r < 4; r++) {
          const int crow = wr * 64 + mi * 16 + lq * 4 + r;
          ldst[ccol * 128 + crow] = f2b(acc[mi][ni][r] + bv);
        }
      }
    }
    __syncthreads();
    const int c = tid >> 2, j0 = (tid & 3) * 32;
    ushort* dst = outVt + (size_t)(n0 - DIM + c) * M + m0 + j0;
#pragma unroll
    for (int k2 = 0; k2 < 4; k2++)
      *(uint4*)(dst + k2 * 8) = *(const uint4*)(ldst + c * 128 + j0 + k2 * 8);
  }
}

// ============ Flash attention, swapped-operand 32x32x16 + defer-max ============
__global__ __launch_bounds__(256) void k_attn(const ushort* __restrict__ Qraw,
                                              const ushort* __restrict__ Kb,
                                              const ushort* __restrict__ Vt,
                                              const float* __restrict__ qpart,
                                              const float* __restrict__ g2,
                                              ushort* __restrict__ Ob) {
  __shared__ __align__(16) ushort smem[16384];  // 32KB: Ks [64][128] + Vs [128][64]
  ushort* Ks = smem;
  ushort* Vs = smem + 64 * 128;

  const int tid = threadIdx.x;
  const int l = tid & 63, wid = tid >> 6;
  const int lo = l & 31, hi = l >> 5;

  const int bid = blockIdx.x;                  // grid = 1024
  const int swz = (bid & 7) * 128 + (bid >> 3);
  const int h = swz >> 6;
  const int q0 = (swz & 63) * 128 + wid * 32;

  bf16x8 qf[8];
  {
    float ssum = 0.f;
    const float* pp = qpart + (size_t)(q0 + lo) * 32;
#pragma unroll
    for (int i = 0; i < 8; i++) {
      float4 t = *(const float4*)(pp + i * 4);
      ssum += t.x + t.y + t.z + t.w;
    }
    const float qs = rsqrtf(ssum * (1.0f / DIM) + 1e-6f);
    const ushort* qp = Qraw + (size_t)(q0 + lo) * DIM + h * HD + hi * 8;
    const float* gp = g2 + h * HD + hi * 8;
#pragma unroll
    for (int ds = 0; ds < 8; ds++) {
      union { uint4 u; ushort us[8]; } rw;
      rw.u = *(const uint4*)(qp + ds * 16);
      float4 ga_ = *(const float4*)(gp + ds * 16);
      float4 gb_ = *(const float4*)(gp + ds * 16 + 4);
      union { uint32_t w[4]; bf16x8 v; } ov;
      ov.w[0] = pk2(b2f(rw.us[0]) * qs * ga_.x, b2f(rw.us[1]) * qs * ga_.y);
      ov.w[1] = pk2(b2f(rw.us[2]) * qs * ga_.z, b2f(rw.us[3]) * qs * ga_.w);
      ov.w[2] = pk2(b2f(rw.us[4]) * qs * gb_.x, b2f(rw.us[5]) * qs * gb_.y);
      ov.w[3] = pk2(b2f(rw.us[6]) * qs * gb_.z, b2f(rw.us[7]) * qs * gb_.w);
      qf[ds] = ov.v;
    }
  }

  f32x16_t o[4] = {};          // O^T: lane q = lo, d = nt*32 + crow(r,hi)
  float m_run = -1e30f, l_run = 0.f;

  for (int kvb = 0; kvb < S_SEQ / 64; kvb++) {
    __syncthreads();
#pragma unroll
    for (int i = 0; i < 4; i++) {
      const int c = i * 256 + tid, row = c >> 4, cs = c & 15;
      gll16(Kb + (size_t)(kvb * 64 + row) * DIM + h * HD + ((cs ^ (row & 7)) * 8),
            Ks + c * 8);
    }
#pragma unroll
    for (int i = 0; i < 4; i++) {
      const int c = i * 256 + tid, row = c >> 3, cs = c & 7;
      gll16(Vt + (size_t)(h * HD + row) * S_SEQ + kvb * 64 + ((cs ^ (row & 7)) * 8),
            Vs + c * 8);
    }
    __syncthreads();

    f32x16_t sA = {}, sB = {};
#pragma unroll
    for (int ds = 0; ds < 8; ds++) {
      const int ch = ((hi + ds * 2) ^ (lo & 7)) * 8;
      bf16x8 kA = *(const bf16x8*)(Ks + lo * 128 + ch);
      bf16x8 kB = *(const bf16x8*)(Ks + (32 + lo) * 128 + ch);
      sA = __builtin_amdgcn_mfma_f32_32x32x16_bf16(kA, qf[ds], sA, 0, 0, 0);
      sB = __builtin_amdgcn_mfma_f32_32x32x16_bf16(kB, qf[ds], sB, 0, 0, 0);
    }

    float p[32];
#pragma unroll
    for (int i = 0; i < 16; i++) { p[i] = sA[i]; p[16 + i] = sB[i]; }
    float pm = p[0];
#pragma unroll
    for (int i = 1; i < 32; i++) pm = fmaxf(pm, p[i]);
    pm = fmaxf(pm, __shfl_xor(pm, 32));
    // T13 defer-max: skip the O-rescale when no row's max grew past m_run+8.
    // P then bounded by e^8; normalization cancels the scale (refcheck'd idiom).
    if (__all(pm - m_run <= 8.0f)) {
      float ps = 0.f;
#pragma unroll
      for (int i = 0; i < 32; i++) { p[i] = __expf(p[i] - m_run); ps += p[i]; }
      ps += __shfl_xor(ps, 32);
      l_run += ps;
    } else {
      const float mn = fmaxf(m_run, pm);
      const float corr = __expf(m_run - mn);
      m_run = mn;
      float ps = 0.f;
#pragma unroll
      for (int i = 0; i < 32; i++) { p[i] = __expf(p[i] - mn); ps += p[i]; }
      ps += __shfl_xor(ps, 32);
      l_run = l_run * corr + ps;
#pragma unroll
      for (int nt = 0; nt < 4; nt++) o[nt] *= corr;
    }

    uint32_t c[16];
#pragma unroll
    for (int j = 0; j < 16; j++) c[j] = pk2(p[2 * j], p[2 * j + 1]);
    bf16x8 pf[4];
#pragma unroll
    for (int s = 0; s < 4; s++) {
      const uint32_t ca = c[4 * s], cb = c[4 * s + 1], cc = c[4 * s + 2], cd = c[4 * s + 3];
      const uint32_t sa = __shfl_xor(ca, 32), sb = __shfl_xor(cb, 32);
      const uint32_t sc = __shfl_xor(cc, 32), sd = __shfl_xor(cd, 32);
      union { uint32_t u[4]; bf16x8 v; } f;
      f.u[0] = hi ? sc : ca; f.u[1] = hi ? sd : cb;
      f.u[2] = hi ? cc : sa; f.u[3] = hi ? cd : sb;
      pf[s] = f.v;
    }

#pragma unroll
    for (int nt = 0; nt < 4; nt++) {
      const int vrow = nt * 32 + lo;
#pragma unroll
      for (int s = 0; s < 4; s++) {
        bf16x8 vf = *(const bf16x8*)(Vs + vrow * 64 + (((s * 2 + hi) ^ (lo & 7)) * 8));
        o[nt] = __builtin_amdgcn_mfma_f32_32x32x16_bf16(vf, pf[s], o[nt], 0, 0, 0);
      }
    }
  }

  const float inv = 1.0f / l_run;
#pragma unroll
  for (int nt = 0; nt < 4; nt++) o[nt] *= inv;

  __syncthreads();
  float* tb = (float*)smem + wid * (32 * 33);
  const int q2 = l >> 1, dh = (l & 1) * 16;
#pragma unroll
  for (int nt = 0; nt < 4; nt++) {
#pragma unroll
    for (int r = 0; r < 16; r++)
      tb[lo * 33 + ((r & 3) + 8 * (r >> 2) + 4 * hi)] = o[nt][r];
    asm volatile("s_waitcnt lgkmcnt(0)" ::: "memory");
    SBAR();
    ushort tmp[16];
#pragma unroll
    for (int j = 0; j < 16; j++) tmp[j] = f2b(tb[q2 * 33 + dh + j]);
    asm volatile("s_waitcnt lgkmcnt(0)" ::: "memory");
    SBAR();
    const size_t oaddr = (size_t)(q0 + q2) * DIM + h * HD + nt * 32 + dh;
    *(uint4*)(Ob + oaddr) = *(uint4*)tmp;
    *(uint4*)(Ob + oaddr + 8) = *(uint4*)(tmp + 8);
  }
}

extern "C" void kernel_launch(void* const* d_in, const int* in_sizes, int n_in,
                              void* d_out, int out_size, void* d_ws, size_t ws_size,
                              hipStream_t stream) {
  const float* x   = (const float*)d_in[0];
  const float* ctx = (const float*)d_in[1];
  const float* Wq  = (const float*)d_in[2];
  const float* bq  = (const float*)d_in[3];
  const float* Wk  = (const float*)d_in[4];
  const float* bk  = (const float*)d_in[5];
  const float* Wv  = (const float*)d_in[6];
  const float* bv  = (const float*)d_in[7];
  const float* Wo  = (const float*)d_in[8];
  const float* bo  = (const float*)d_in[9];
  const float* gq  = (const float*)d_in[10];
  const float* gk  = (const float*)d_in[11];

  char* ws = (char*)d_ws;
  ushort* wqt    = (ushort*)(ws);                 // [2048][2048] bf16   8.39MB
  ushort* wkt    = (ushort*)(ws + 8388608);       // [2048][4096] bf16  16.78MB } adjacent =>
  ushort* wvt    = (ushort*)(ws + 25165824);      // [2048][4096] bf16  16.78MB } [4096][4096] KV
  ushort* wot    = (ushort*)(ws + 41943040);      // [2048][2048] bf16   8.39MB
  ushort* ctxb   = (ushort*)(ws + 50331648);      // [512][4096]  bf16   4.19MB
  float*  g2     = (float*)(ws + 54558720);       // [2048] f32   8KB
  float*  qpart  = (float*)(ws + 56623104);       // [8192][32] f32  1MB
  ushort* kb     = (ushort*)(ws + 83886080);      // [512][2048]  bf16   2.10MB
  ushort* vt     = (ushort*)(ws + 85983232);      // [2048][512]  bf16   2.10MB
  ushort* xb     = (ushort*)(ws + 88080384);      // [8192][2048] bf16  33.55MB
  ushort* kraw   = (ushort*)(ws + 88080384);      // aliases xb (dead after Qproj)
  ushort* attnb  = (ushort*)(ws + 88080384);      // aliases (kraw dead after knorm)
  ushort* qraw   = (ushort*)(ws + 121634816);     // [8192][2048] bf16  33.55MB

  // 1. preprocessing: casts + weight transposes + G
  k_prep<<<33793, 256, 0, stream>>>(x, ctx, Wq, Wk, Wv, Wo, gq, gk,
                                    xb, ctxb, wqt, wkt, wvt, wot, g2);
  // 2. Q projection: qraw = x@Wq + bq (bf16) + per-row sumsq partials -> qpart
  k_gemm256<1><<<dim3(DIM / 256, L_SEQ / 256), 512, 0, stream>>>(xb, wqt, bq, qraw, qpart, L_SEQ, DIM, DIM);
  // 3. fused K+V projection (depth-6 pipeline)
  k_gemmkv<<<256, 256, 0, stream>>>(ctxb, wkt, bk, bv, kraw, vt);
  // 4. K rms-normalize
  k_knorm<<<S_SEQ, 256, 0, stream>>>(kraw, kb);
  // 5. attention (defer-max online softmax)
  k_attn<<<L_SEQ / 128 * NH, 256, 0, stream>>>(qraw, kb, vt, qpart, g2, attnb);
  // 6. out = attn @ Wo + bo (fp32)
  k_gemm256<0><<<dim3(DIM / 256, L_SEQ / 256), 512, 0, stream>>>(attnb, wot, bo, d_out, nullptr, L_SEQ, DIM, DIM);
}

// Round 15
// 319.025 us; speedup vs baseline: 1.0768x; 1.0768x over previous
//
#include <hip/hip_runtime.h>
#include <hip/hip_bf16.h>
#include <stdint.h>

#define L_SEQ 8192
#define S_SEQ 512
#define DIM   2048
#define CTX   4096
#define NH    16
#define HD    128

typedef __bf16 bf16_t;
typedef bf16_t bf16x8 __attribute__((ext_vector_type(8)));
typedef float  f32x4_t __attribute__((ext_vector_type(4)));
typedef float  f32x16_t __attribute__((ext_vector_type(16)));

__device__ __forceinline__ ushort f2b(float f) {
  bf16_t h = (bf16_t)f;
  return __builtin_bit_cast(ushort, h);
}
__device__ __forceinline__ uint32_t pk2(float a, float b) {
  return (uint32_t)f2b(a) | ((uint32_t)f2b(b) << 16);
}
__device__ __forceinline__ float b2f(ushort u) {
  union { uint32_t u; float f; } v; v.u = ((uint32_t)u) << 16;
  return v.f;
}
__device__ __forceinline__ void gll16(const ushort* g, ushort* l) {
  __builtin_amdgcn_global_load_lds((const __attribute__((address_space(1))) void*)g,
                                   (__attribute__((address_space(3))) void*)l, 16, 0, 0);
}
#define SBAR() __builtin_amdgcn_sched_barrier(0)

// ============ fused preprocessing: x/ctx casts + 4 weight transposes + G ============
__global__ __launch_bounds__(256) void k_prep(const float* __restrict__ x,
                                              const float* __restrict__ ctx,
                                              const float* __restrict__ Wq,
                                              const float* __restrict__ Wk,
                                              const float* __restrict__ Wv,
                                              const float* __restrict__ Wo,
                                              const float* __restrict__ gq,
                                              const float* __restrict__ gk,
                                              ushort* __restrict__ xb,
                                              ushort* __restrict__ ctxb,
                                              ushort* __restrict__ wqt,
                                              ushort* __restrict__ wkt,
                                              ushort* __restrict__ wvt,
                                              ushort* __restrict__ wot,
                                              float* __restrict__ g2) {
  const int b = blockIdx.x;
  const int tid = threadIdx.x;
  if (b == 33792) {  // G = gq*gk/sqrt(HD)
    const int d = tid * 8;
#pragma unroll
    for (int j = 0; j < 8; j++) g2[d + j] = gq[d + j] * gk[d + j] * 0.08838834764831843f;
    return;
  }
  if (b < 9216) {  // elementwise casts
    const float* src; ushort* dst; size_t i;
    if (b < 8192) { src = x;   dst = xb;   i = ((size_t)b * 256 + tid) * 8; }
    else          { src = ctx; dst = ctxb; i = ((size_t)(b - 8192) * 256 + tid) * 8; }
    float4 a = *(const float4*)(src + i);
    float4 c = *(const float4*)(src + i + 4);
    uint4 r;
    r.x = pk2(a.x, a.y); r.y = pk2(a.z, a.w);
    r.z = pk2(c.x, c.y); r.w = pk2(c.z, c.w);
    *(uint4*)(dst + i) = r;
    return;
  }
  // transpose + cast fp32 [K][2048] -> bf16 [2048][K]
  __shared__ float t[32][33];
  const float* src; ushort* dst; int K, ti;
  if (b < 13312)      { src = Wq; dst = wqt; K = DIM; ti = b - 9216; }
  else if (b < 21504) { src = Wk; dst = wkt; K = CTX; ti = b - 13312; }
  else if (b < 29696) { src = Wv; dst = wvt; K = CTX; ti = b - 21504; }
  else                { src = Wo; dst = wot; K = DIM; ti = b - 29696; }
  const int n0 = (ti & 63) * 32, k0 = (ti >> 6) * 32;
  const int tx = tid & 31, ty = tid >> 5;
#pragma unroll
  for (int i = 0; i < 4; i++)
    t[ty + 8 * i][tx] = src[(size_t)(k0 + ty + 8 * i) * DIM + n0 + tx];
  __syncthreads();
#pragma unroll
  for (int i = 0; i < 4; i++)
    dst[(size_t)(n0 + ty + 8 * i) * K + k0 + tx] = f2b(t[tx][ty + 8 * i]);
}

// ============ K rms-normalize (512 rows) ============
__global__ __launch_bounds__(256) void k_knorm(const ushort* __restrict__ kraw,
                                               ushort* __restrict__ kb) {
  const int row = blockIdx.x, tid = threadIdx.x;
  uint4 v = *(const uint4*)(kraw + (size_t)row * DIM + tid * 8);
  const uint32_t* vu = (const uint32_t*)&v;
  float f[8];
#pragma unroll
  for (int i = 0; i < 4; i++) {
    f[2 * i]     = b2f((ushort)(vu[i] & 0xffffu));
    f[2 * i + 1] = b2f((ushort)(vu[i] >> 16));
  }
  float s = 0.f;
#pragma unroll
  for (int i = 0; i < 8; i++) s += f[i] * f[i];
#pragma unroll
  for (int off = 32; off; off >>= 1) s += __shfl_down(s, off);
  __shared__ float wsum[4];
  __shared__ float rtot;
  if ((tid & 63) == 0) wsum[tid >> 6] = s;
  __syncthreads();
  if (tid == 0)
    rtot = rsqrtf((wsum[0] + wsum[1] + wsum[2] + wsum[3]) * (1.0f / DIM) + 1e-6f);
  __syncthreads();
  const float rms = rtot;
  ushort r[8];
#pragma unroll
  for (int i = 0; i < 8; i++) r[i] = f2b(f[i] * rms);
  *(uint4*)(kb + (size_t)row * DIM + tid * 8) = *(uint4*)r;
}

// ======================= 256x256 8-wave 4-phase GEMM (round-12 schedule) ==========
template <int OUT_MODE>
__global__ __launch_bounds__(512, 2) void k_gemm256(const ushort* __restrict__ A,
                                                    const ushort* __restrict__ Bt,
                                                    const float* __restrict__ bias,
                                                    void* __restrict__ outp,
                                                    float* __restrict__ qpart,
                                                    int M, int N, int K) {
  __shared__ __align__(16) ushort lds[65536];  // 128 KB
  const int tid = threadIdx.x;
  const int l = tid & 63, wid = tid >> 6;
  const int wm = wid >> 2, wn = wid & 3;
  const int lr = l & 15, lq = l >> 4;

  const int nwg = gridDim.x * gridDim.y;
  const int bid = blockIdx.y * gridDim.x + blockIdx.x;
  const int swz = (bid & 7) * (nwg >> 3) + (bid >> 3);
  const int m0 = (swz / gridDim.x) * 256, n0 = (swz % gridDim.x) * 256;

  f32x4_t acc[8][4];
#pragma unroll
  for (int i = 0; i < 8; i++)
#pragma unroll
    for (int j = 0; j < 4; j++) acc[i][j] = f32x4_t{0.f, 0.f, 0.f, 0.f};

  const int srow = l >> 3;
  const int schunk = ((l & 7) ^ (srow & 7)) * 8;
  auto stage = [&](int buf, int tile, int mat, int h) {
    const ushort* gp = mat ? Bt : A;
    const int rn0 = mat ? n0 : m0;
    const size_t r0 = (size_t)(rn0 + h * 128 + wid * 8 + srow);
    const ushort* g0 = gp + r0 * K + tile * 64 + schunk;
    ushort* l0 = &lds[buf * 32768 + mat * 16384 + (h * 128 + wid * 8) * 64];
    gll16(g0, l0);
    gll16(g0 + (size_t)64 * K, l0 + 64 * 64);
  };

  auto rdA = [&](int buf, int mf, int ks) -> bf16x8 {
    const int R = wm * 128 + mf * 16 + lr;
    return *(const bf16x8*)(&lds[buf * 32768 + R * 64 + (((ks * 4 + lq) ^ (R & 7)) * 8)]);
  };
  auto rdB = [&](int buf, int nf, int ks) -> bf16x8 {
    const int R = wn * 64 + nf * 16 + lr;
    return *(const bf16x8*)(&lds[buf * 32768 + 16384 + R * 64 + (((ks * 4 + lq) ^ (R & 7)) * 8)]);
  };

  const int NT = K >> 6;
  stage(0, 0, 0, 0); stage(0, 0, 0, 1); stage(0, 0, 1, 0); stage(0, 0, 1, 1);

  bf16x8 a[4][2], a2[4][2], b[2][2], b2[2][2];
  for (int kt = 0; kt < NT; kt++) {
    const int cur = kt & 1, nxt = cur ^ 1;
    const bool pf = (kt + 1 < NT);
    if (pf) { stage(nxt, kt + 1, 0, 0); asm volatile("s_waitcnt vmcnt(2)" ::: "memory"); }
    else    { asm volatile("s_waitcnt vmcnt(0)" ::: "memory"); }
    SBAR();
    __builtin_amdgcn_s_barrier();
    SBAR();
#pragma unroll
    for (int mf = 0; mf < 4; mf++) { a[mf][0] = rdA(cur, mf, 0); a[mf][1] = rdA(cur, mf, 1); }
#pragma unroll
    for (int nf = 0; nf < 2; nf++) { b[nf][0] = rdB(cur, nf, 0); b[nf][1] = rdB(cur, nf, 1); }
    __builtin_amdgcn_s_setprio(1);
#pragma unroll
    for (int mf = 0; mf < 4; mf++)
#pragma unroll
      for (int nf = 0; nf < 2; nf++) {
        acc[mf][nf] = __builtin_amdgcn_mfma_f32_16x16x32_bf16(a[mf][0], b[nf][0], acc[mf][nf], 0, 0, 0);
        acc[mf][nf] = __builtin_amdgcn_mfma_f32_16x16x32_bf16(a[mf][1], b[nf][1], acc[mf][nf], 0, 0, 0);
      }
    __builtin_amdgcn_s_setprio(0);
    SBAR();
    __builtin_amdgcn_s_barrier();
    SBAR();
#pragma unroll
    for (int mf = 0; mf < 4; mf++) { a2[mf][0] = rdA(cur, mf + 4, 0); a2[mf][1] = rdA(cur, mf + 4, 1); }
    if (pf) stage(nxt, kt + 1, 0, 1);
    SBAR();
    __builtin_amdgcn_s_barrier();
    SBAR();
    __builtin_amdgcn_s_setprio(1);
#pragma unroll
    for (int mf = 0; mf < 4; mf++)
#pragma unroll
      for (int nf = 0; nf < 2; nf++) {
        acc[mf + 4][nf] = __builtin_amdgcn_mfma_f32_16x16x32_bf16(a2[mf][0], b[nf][0], acc[mf + 4][nf], 0, 0, 0);
        acc[mf + 4][nf] = __builtin_amdgcn_mfma_f32_16x16x32_bf16(a2[mf][1], b[nf][1], acc[mf + 4][nf], 0, 0, 0);
      }
    __builtin_amdgcn_s_setprio(0);
    SBAR();
    __builtin_amdgcn_s_barrier();
    SBAR();
#pragma unroll
    for (int nf = 0; nf < 2; nf++) { b2[nf][0] = rdB(cur, nf + 2, 0); b2[nf][1] = rdB(cur, nf + 2, 1); }
    if (pf) stage(nxt, kt + 1, 1, 0);
    SBAR();
    __builtin_amdgcn_s_barrier();
    SBAR();
    __builtin_amdgcn_s_setprio(1);
#pragma unroll
    for (int mf = 0; mf < 4; mf++)
#pragma unroll
      for (int nf = 0; nf < 2; nf++) {
        acc[mf + 4][nf + 2] = __builtin_amdgcn_mfma_f32_16x16x32_bf16(a2[mf][0], b2[nf][0], acc[mf + 4][nf + 2], 0, 0, 0);
        acc[mf + 4][nf + 2] = __builtin_amdgcn_mfma_f32_16x16x32_bf16(a2[mf][1], b2[nf][1], acc[mf + 4][nf + 2], 0, 0, 0);
      }
    __builtin_amdgcn_s_setprio(0);
    SBAR();
    __builtin_amdgcn_s_barrier();
    SBAR();
#pragma unroll
    for (int mf = 0; mf < 4; mf++) { a[mf][0] = rdA(cur, mf, 0); a[mf][1] = rdA(cur, mf, 1); }
    if (pf) stage(nxt, kt + 1, 1, 1);
    SBAR();
    __builtin_amdgcn_s_barrier();
    SBAR();
    __builtin_amdgcn_s_setprio(1);
#pragma unroll
    for (int mf = 0; mf < 4; mf++)
#pragma unroll
      for (int nf = 0; nf < 2; nf++) {
        acc[mf][nf + 2] = __builtin_amdgcn_mfma_f32_16x16x32_bf16(a[mf][0], b2[nf][0], acc[mf][nf + 2], 0, 0, 0);
        acc[mf][nf + 2] = __builtin_amdgcn_mfma_f32_16x16x32_bf16(a[mf][1], b2[nf][1], acc[mf][nf + 2], 0, 0, 0);
      }
    __builtin_amdgcn_s_setprio(0);
    SBAR();
    __builtin_amdgcn_s_barrier();
    SBAR();
  }

  // ---- epilogue ----
  float bvs[4];
#pragma unroll
  for (int nf = 0; nf < 4; nf++) bvs[nf] = bias[n0 + wn * 64 + nf * 16 + lr];
#pragma unroll
  for (int nf = 0; nf < 4; nf++) {
    const int col = n0 + wn * 64 + nf * 16 + lr;
#pragma unroll
    for (int mf = 0; mf < 8; mf++) {
#pragma unroll
      for (int r = 0; r < 4; r++) {
        const int row = m0 + wm * 128 + mf * 16 + lq * 4 + r;
        const float v = acc[mf][nf][r] + bvs[nf];
        if constexpr (OUT_MODE == 0)
          ((float*)outp)[(size_t)row * N + col] = v;
        else
          ((ushort*)outp)[(size_t)row * N + col] = f2b(v);
      }
    }
  }
  if constexpr (OUT_MODE == 1) {
    const int slot = (n0 >> 8) * 4 + wn;
#pragma unroll
    for (int mf = 0; mf < 8; mf++) {
#pragma unroll
      for (int r = 0; r < 4; r++) {
        float s = 0.f;
#pragma unroll
        for (int nf = 0; nf < 4; nf++) {
          const float v = acc[mf][nf][r] + bvs[nf];
          s += v * v;
        }
        s += __shfl_xor(s, 1); s += __shfl_xor(s, 2);
        s += __shfl_xor(s, 4); s += __shfl_xor(s, 8);
        if (lr == 0)
          qpart[(size_t)(m0 + wm * 128 + mf * 16 + lq * 4 + r) * 32 + slot] = s;
      }
    }
  }
}

// ============ KV projection GEMM: depth-6 pipeline (5-tile load lead) ============
__global__ __launch_bounds__(256) void k_gemmkv(const ushort* __restrict__ A,
                                                const ushort* __restrict__ Bt,
                                                const float* __restrict__ biasK,
                                                const float* __restrict__ biasV,
                                                ushort* __restrict__ outK,
                                                ushort* __restrict__ outVt) {
  __shared__ __align__(16) ushort As[6][128 * 32];  // 48 KB
  __shared__ __align__(16) ushort Bs[6][64 * 32];   // 24 KB
  const int tid = threadIdx.x;
  const int l = tid & 63, wid = tid >> 6;
  const int wr = wid >> 1, wc = wid & 1;
  const int lr = l & 15, lq = l >> 4;
  const int K = CTX, M = S_SEQ;

  const int bid = blockIdx.x;                 // grid = 256
  const int swz = (bid & 7) * 32 + (bid >> 3);
  const int n0 = (swz >> 2) * 64, m0 = (swz & 3) * 128;

  f32x4_t acc[4][2];
#pragma unroll
  for (int i = 0; i < 4; i++)
#pragma unroll
    for (int j = 0; j < 2; j++) acc[i][j] = f32x4_t{0.f, 0.f, 0.f, 0.f};

  const int srow = l >> 2;
  const int schunk = ((l & 3) ^ ((srow >> 1) & 3)) * 8;
  const ushort* gA = A  + (size_t)(m0 + srow) * K + schunk;
  const ushort* gB = Bt + (size_t)(n0 + wid * 16 + srow) * K + schunk;

  auto stage = [&](int buf, int kt) {
    const int ko = kt * 32;
    gll16(gA + (size_t)(wid * 16) * K + ko,      &As[buf][(wid * 16) * 32]);
    gll16(gA + (size_t)(64 + wid * 16) * K + ko, &As[buf][(64 + wid * 16) * 32]);
    gll16(gB + ko,                               &Bs[buf][(wid * 16) * 32]);
  };
  auto rdA = [&](int buf, int mi) -> bf16x8 {
    const int R = wr * 64 + mi * 16 + lr;
    return *(const bf16x8*)(&As[buf][R * 32 + ((lq ^ ((R >> 1) & 3)) * 8)]);
  };
  auto rdB = [&](int buf, int ni) -> bf16x8 {
    const int R = wc * 32 + ni * 16 + lr;
    return *(const bf16x8*)(&Bs[buf][R * 32 + ((lq ^ ((R >> 1) & 3)) * 8)]);
  };

  const int NT = K >> 5;  // 128
  stage(0, 0); stage(1, 1); stage(2, 2); stage(3, 3); stage(4, 4);
  int cur = 0;
  for (int t = 0; t < NT; t++) {
    if (t + 5 < NT) {
      const int prv = (cur == 0) ? 5 : cur - 1;
      stage(prv, t + 5);
      asm volatile("s_waitcnt vmcnt(15)" ::: "memory");
    }
    else if (t + 4 < NT) { asm volatile("s_waitcnt vmcnt(12)" ::: "memory"); }
    else if (t + 3 < NT) { asm volatile("s_waitcnt vmcnt(9)" ::: "memory"); }
    else if (t + 2 < NT) { asm volatile("s_waitcnt vmcnt(6)" ::: "memory"); }
    else if (t + 1 < NT) { asm volatile("s_waitcnt vmcnt(3)" ::: "memory"); }
    else                 { asm volatile("s_waitcnt vmcnt(0)" ::: "memory"); }
    SBAR();
    __builtin_amdgcn_s_barrier();
    SBAR();

    bf16x8 af[4], bfr[2];
#pragma unroll
    for (int mi = 0; mi < 4; mi++) af[mi] = rdA(cur, mi);
#pragma unroll
    for (int ni = 0; ni < 2; ni++) bfr[ni] = rdB(cur, ni);
    __builtin_amdgcn_s_setprio(1);
#pragma unroll
    for (int mi = 0; mi < 4; mi++)
#pragma unroll
      for (int ni = 0; ni < 2; ni++)
        acc[mi][ni] = __builtin_amdgcn_mfma_f32_16x16x32_bf16(af[mi], bfr[ni], acc[mi][ni], 0, 0, 0);
    __builtin_amdgcn_s_setprio(0);
    SBAR();
    __builtin_amdgcn_s_barrier();
    SBAR();
    cur = (cur == 5) ? 0 : cur + 1;
  }

  if (n0 < DIM) {
#pragma unroll
    for (int mi = 0; mi < 4; mi++) {
#pragma unroll
      for (int ni = 0; ni < 2; ni++) {
        const int col = n0 + wc * 32 + ni * 16 + lr;
        const float bv = biasK[col];
#pragma unroll
        for (int r = 0; r < 4; r++) {
          const int row = m0 + wr * 64 + mi * 16 + lq * 4 + r;
          outK[(size_t)row * DIM + col] = f2b(acc[mi][ni][r] + bv);
        }
      }
    }
  } else {
    // V block: transpose through LDS for coalesced V^T stores
    ushort* ldst = &As[0][0];
    __syncthreads();
#pragma unroll
    for (int mi = 0; mi < 4; mi++) {
#pragma unroll
      for (int ni = 0; ni < 2; ni++) {
        const int ccol = wc * 32 + ni * 16 + lr;
        const float bv = biasV[n0 - DIM + ccol];
#pragma unroll
        for (int r = 0; r < 4; r++) {
          const int crow = wr * 64 + mi * 16 + lq * 4 + r;
          ldst[ccol * 128 + crow] = f2b(acc[mi][ni][r] + bv);
        }
      }
    }
    __syncthreads();
    const int c = tid >> 2, j0 = (tid & 3) * 32;
    ushort* dst = outVt + (size_t)(n0 - DIM + c) * M + m0 + j0;
#pragma unroll
    for (int k2 = 0; k2 < 4; k2++)
      *(uint4*)(dst + k2 * 8) = *(const uint4*)(ldst + c * 128 + j0 + k2 * 8);
  }
}

// ============ Flash attention, swapped-operand 32x32x16 (R13 softmax) ============
__global__ __launch_bounds__(256) void k_attn(const ushort* __restrict__ Qraw,
                                              const ushort* __restrict__ Kb,
                                              const ushort* __restrict__ Vt,
                                              const float* __restrict__ qpart,
                                              const float* __restrict__ g2,
                                              ushort* __restrict__ Ob) {
  __shared__ __align__(16) ushort smem[16384];  // 32KB: Ks [64][128] + Vs [128][64]
  ushort* Ks = smem;
  ushort* Vs = smem + 64 * 128;

  const int tid = threadIdx.x;
  const int l = tid & 63, wid = tid >> 6;
  const int lo = l & 31, hi = l >> 5;

  const int bid = blockIdx.x;                  // grid = 1024
  const int swz = (bid & 7) * 128 + (bid >> 3);
  const int h = swz >> 6;
  const int q0 = (swz & 63) * 128 + wid * 32;

  bf16x8 qf[8];
  {
    float ssum = 0.f;
    const float* pp = qpart + (size_t)(q0 + lo) * 32;
#pragma unroll
    for (int i = 0; i < 8; i++) {
      float4 t = *(const float4*)(pp + i * 4);
      ssum += t.x + t.y + t.z + t.w;
    }
    const float qs = rsqrtf(ssum * (1.0f / DIM) + 1e-6f);
    const ushort* qp = Qraw + (size_t)(q0 + lo) * DIM + h * HD + hi * 8;
    const float* gp = g2 + h * HD + hi * 8;
#pragma unroll
    for (int ds = 0; ds < 8; ds++) {
      union { uint4 u; ushort us[8]; } rw;
      rw.u = *(const uint4*)(qp + ds * 16);
      float4 ga_ = *(const float4*)(gp + ds * 16);
      float4 gb_ = *(const float4*)(gp + ds * 16 + 4);
      union { uint32_t w[4]; bf16x8 v; } ov;
      ov.w[0] = pk2(b2f(rw.us[0]) * qs * ga_.x, b2f(rw.us[1]) * qs * ga_.y);
      ov.w[1] = pk2(b2f(rw.us[2]) * qs * ga_.z, b2f(rw.us[3]) * qs * ga_.w);
      ov.w[2] = pk2(b2f(rw.us[4]) * qs * gb_.x, b2f(rw.us[5]) * qs * gb_.y);
      ov.w[3] = pk2(b2f(rw.us[6]) * qs * gb_.z, b2f(rw.us[7]) * qs * gb_.w);
      qf[ds] = ov.v;
    }
  }

  f32x16_t o[4] = {};          // O^T: lane q = lo, d = nt*32 + crow(r,hi)
  float m_run = -1e30f, l_run = 0.f;

  for (int kvb = 0; kvb < S_SEQ / 64; kvb++) {
    __syncthreads();
#pragma unroll
    for (int i = 0; i < 4; i++) {
      const int c = i * 256 + tid, row = c >> 4, cs = c & 15;
      gll16(Kb + (size_t)(kvb * 64 + row) * DIM + h * HD + ((cs ^ (row & 7)) * 8),
            Ks + c * 8);
    }
#pragma unroll
    for (int i = 0; i < 4; i++) {
      const int c = i * 256 + tid, row = c >> 3, cs = c & 7;
      gll16(Vt + (size_t)(h * HD + row) * S_SEQ + kvb * 64 + ((cs ^ (row & 7)) * 8),
            Vs + c * 8);
    }
    __syncthreads();

    f32x16_t sA = {}, sB = {};
#pragma unroll
    for (int ds = 0; ds < 8; ds++) {
      const int ch = ((hi + ds * 2) ^ (lo & 7)) * 8;
      bf16x8 kA = *(const bf16x8*)(Ks + lo * 128 + ch);
      bf16x8 kB = *(const bf16x8*)(Ks + (32 + lo) * 128 + ch);
      sA = __builtin_amdgcn_mfma_f32_32x32x16_bf16(kA, qf[ds], sA, 0, 0, 0);
      sB = __builtin_amdgcn_mfma_f32_32x32x16_bf16(kB, qf[ds], sB, 0, 0, 0);
    }

    float p[32];
#pragma unroll
    for (int i = 0; i < 16; i++) { p[i] = sA[i]; p[16 + i] = sB[i]; }
    float pm = p[0];
#pragma unroll
    for (int i = 1; i < 32; i++) pm = fmaxf(pm, p[i]);
    pm = fmaxf(pm, __shfl_xor(pm, 32));
    const float mn = fmaxf(m_run, pm);
    const float corr = __expf(m_run - mn);
    m_run = mn;
    float ps = 0.f;
#pragma unroll
    for (int i = 0; i < 32; i++) { p[i] = __expf(p[i] - mn); ps += p[i]; }
    ps += __shfl_xor(ps, 32);
    l_run = l_run * corr + ps;
#pragma unroll
    for (int nt = 0; nt < 4; nt++) o[nt] *= corr;

    uint32_t c[16];
#pragma unroll
    for (int j = 0; j < 16; j++) c[j] = pk2(p[2 * j], p[2 * j + 1]);
    bf16x8 pf[4];
#pragma unroll
    for (int s = 0; s < 4; s++) {
      const uint32_t ca = c[4 * s], cb = c[4 * s + 1], cc = c[4 * s + 2], cd = c[4 * s + 3];
      const uint32_t sa = __shfl_xor(ca, 32), sb = __shfl_xor(cb, 32);
      const uint32_t sc = __shfl_xor(cc, 32), sd = __shfl_xor(cd, 32);
      union { uint32_t u[4]; bf16x8 v; } f;
      f.u[0] = hi ? sc : ca; f.u[1] = hi ? sd : cb;
      f.u[2] = hi ? cc : sa; f.u[3] = hi ? cd : sb;
      pf[s] = f.v;
    }

#pragma unroll
    for (int nt = 0; nt < 4; nt++) {
      const int vrow = nt * 32 + lo;
#pragma unroll
      for (int s = 0; s < 4; s++) {
        bf16x8 vf = *(const bf16x8*)(Vs + vrow * 64 + (((s * 2 + hi) ^ (lo & 7)) * 8));
        o[nt] = __builtin_amdgcn_mfma_f32_32x32x16_bf16(vf, pf[s], o[nt], 0, 0, 0);
      }
    }
  }

  const float inv = 1.0f / l_run;
#pragma unroll
  for (int nt = 0; nt < 4; nt++) o[nt] *= inv;

  __syncthreads();
  float* tb = (float*)smem + wid * (32 * 33);
  const int q2 = l >> 1, dh = (l & 1) * 16;
#pragma unroll
  for (int nt = 0; nt < 4; nt++) {
#pragma unroll
    for (int r = 0; r < 16; r++)
      tb[lo * 33 + ((r & 3) + 8 * (r >> 2) + 4 * hi)] = o[nt][r];
    asm volatile("s_waitcnt lgkmcnt(0)" ::: "memory");
    SBAR();
    ushort tmp[16];
#pragma unroll
    for (int j = 0; j < 16; j++) tmp[j] = f2b(tb[q2 * 33 + dh + j]);
    asm volatile("s_waitcnt lgkmcnt(0)" ::: "memory");
    SBAR();
    const size_t oaddr = (size_t)(q0 + q2) * DIM + h * HD + nt * 32 + dh;
    *(uint4*)(Ob + oaddr) = *(uint4*)tmp;
    *(uint4*)(Ob + oaddr + 8) = *(uint4*)(tmp + 8);
  }
}

extern "C" void kernel_launch(void* const* d_in, const int* in_sizes, int n_in,
                              void* d_out, int out_size, void* d_ws, size_t ws_size,
                              hipStream_t stream) {
  const float* x   = (const float*)d_in[0];
  const float* ctx = (const float*)d_in[1];
  const float* Wq  = (const float*)d_in[2];
  const float* bq  = (const float*)d_in[3];
  const float* Wk  = (const float*)d_in[4];
  const float* bk  = (const float*)d_in[5];
  const float* Wv  = (const float*)d_in[6];
  const float* bv  = (const float*)d_in[7];
  const float* Wo  = (const float*)d_in[8];
  const float* bo  = (const float*)d_in[9];
  const float* gq  = (const float*)d_in[10];
  const float* gk  = (const float*)d_in[11];

  char* ws = (char*)d_ws;
  ushort* wqt    = (ushort*)(ws);                 // [2048][2048] bf16   8.39MB
  ushort* wkt    = (ushort*)(ws + 8388608);       // [2048][4096] bf16  16.78MB } adjacent =>
  ushort* wvt    = (ushort*)(ws + 25165824);      // [2048][4096] bf16  16.78MB } [4096][4096] KV
  ushort* wot    = (ushort*)(ws + 41943040);      // [2048][2048] bf16   8.39MB
  ushort* ctxb   = (ushort*)(ws + 50331648);      // [512][4096]  bf16   4.19MB
  float*  g2     = (float*)(ws + 54558720);       // [2048] f32   8KB
  float*  qpart  = (float*)(ws + 56623104);       // [8192][32] f32  1MB
  ushort* kb     = (ushort*)(ws + 83886080);      // [512][2048]  bf16   2.10MB
  ushort* vt     = (ushort*)(ws + 85983232);      // [2048][512]  bf16   2.10MB
  ushort* xb     = (ushort*)(ws + 88080384);      // [8192][2048] bf16  33.55MB
  ushort* kraw   = (ushort*)(ws + 88080384);      // aliases xb (dead after Qproj)
  ushort* attnb  = (ushort*)(ws + 88080384);      // aliases (kraw dead after knorm)
  ushort* qraw   = (ushort*)(ws + 121634816);     // [8192][2048] bf16  33.55MB

  // 1. preprocessing: casts + weight transposes + G
  k_prep<<<33793, 256, 0, stream>>>(x, ctx, Wq, Wk, Wv, Wo, gq, gk,
                                    xb, ctxb, wqt, wkt, wvt, wot, g2);
  // 2. Q projection: qraw = x@Wq + bq (bf16) + per-row sumsq partials -> qpart
  k_gemm256<1><<<dim3(DIM / 256, L_SEQ / 256), 512, 0, stream>>>(xb, wqt, bq, qraw, qpart, L_SEQ, DIM, DIM);
  // 3. fused K+V projection (depth-6 pipeline)
  k_gemmkv<<<256, 256, 0, stream>>>(ctxb, wkt, bk, bv, kraw, vt);
  // 4. K rms-normalize
  k_knorm<<<S_SEQ, 256, 0, stream>>>(kraw, kb);
  // 5. attention
  k_attn<<<L_SEQ / 128 * NH, 256, 0, stream>>>(qraw, kb, vt, qpart, g2, attnb);
  // 6. out = attn @ Wo + bo (fp32)
  k_gemm256<0><<<dim3(DIM / 256, L_SEQ / 256), 512, 0, stream>>>(attnb, wot, bo, d_out, nullptr, L_SEQ, DIM, DIM);
}

// Round 16
// 315.829 us; speedup vs baseline: 1.0877x; 1.0101x over previous
//
#include <hip/hip_runtime.h>
#include <hip/hip_bf16.h>
#include <stdint.h>

#define L_SEQ 8192
#define S_SEQ 512
#define DIM   2048
#define CTX   4096
#define NH    16
#define HD    128

typedef __bf16 bf16_t;
typedef bf16_t bf16x8 __attribute__((ext_vector_type(8)));
typedef float  f32x4_t __attribute__((ext_vector_type(4)));
typedef float  f32x16_t __attribute__((ext_vector_type(16)));

__device__ __forceinline__ ushort f2b(float f) {
  bf16_t h = (bf16_t)f;
  return __builtin_bit_cast(ushort, h);
}
__device__ __forceinline__ uint32_t pk2(float a, float b) {
  return (uint32_t)f2b(a) | ((uint32_t)f2b(b) << 16);
}
__device__ __forceinline__ float b2f(ushort u) {
  union { uint32_t u; float f; } v; v.u = ((uint32_t)u) << 16;
  return v.f;
}
__device__ __forceinline__ void gll16(const ushort* g, ushort* l) {
  __builtin_amdgcn_global_load_lds((const __attribute__((address_space(1))) void*)g,
                                   (__attribute__((address_space(3))) void*)l, 16, 0, 0);
}
#define SBAR() __builtin_amdgcn_sched_barrier(0)

// ============ fused preprocessing: x/ctx casts + 4 weight transposes + G ============
__global__ __launch_bounds__(256) void k_prep(const float* __restrict__ x,
                                              const float* __restrict__ ctx,
                                              const float* __restrict__ Wq,
                                              const float* __restrict__ Wk,
                                              const float* __restrict__ Wv,
                                              const float* __restrict__ Wo,
                                              const float* __restrict__ gq,
                                              const float* __restrict__ gk,
                                              ushort* __restrict__ xb,
                                              ushort* __restrict__ ctxb,
                                              ushort* __restrict__ wqt,
                                              ushort* __restrict__ wkt,
                                              ushort* __restrict__ wvt,
                                              ushort* __restrict__ wot,
                                              float* __restrict__ g2) {
  const int b = blockIdx.x;
  const int tid = threadIdx.x;
  if (b == 33792) {  // G = gq*gk/sqrt(HD)
    const int d = tid * 8;
#pragma unroll
    for (int j = 0; j < 8; j++) g2[d + j] = gq[d + j] * gk[d + j] * 0.08838834764831843f;
    return;
  }
  if (b < 9216) {  // elementwise casts
    const float* src; ushort* dst; size_t i;
    if (b < 8192) { src = x;   dst = xb;   i = ((size_t)b * 256 + tid) * 8; }
    else          { src = ctx; dst = ctxb; i = ((size_t)(b - 8192) * 256 + tid) * 8; }
    float4 a = *(const float4*)(src + i);
    float4 c = *(const float4*)(src + i + 4);
    uint4 r;
    r.x = pk2(a.x, a.y); r.y = pk2(a.z, a.w);
    r.z = pk2(c.x, c.y); r.w = pk2(c.z, c.w);
    *(uint4*)(dst + i) = r;
    return;
  }
  // transpose + cast fp32 [K][2048] -> bf16 [2048][K]
  __shared__ float t[32][33];
  const float* src; ushort* dst; int K, ti;
  if (b < 13312)      { src = Wq; dst = wqt; K = DIM; ti = b - 9216; }
  else if (b < 21504) { src = Wk; dst = wkt; K = CTX; ti = b - 13312; }
  else if (b < 29696) { src = Wv; dst = wvt; K = CTX; ti = b - 21504; }
  else                { src = Wo; dst = wot; K = DIM; ti = b - 29696; }
  const int n0 = (ti & 63) * 32, k0 = (ti >> 6) * 32;
  const int tx = tid & 31, ty = tid >> 5;
#pragma unroll
  for (int i = 0; i < 4; i++)
    t[ty + 8 * i][tx] = src[(size_t)(k0 + ty + 8 * i) * DIM + n0 + tx];
  __syncthreads();
#pragma unroll
  for (int i = 0; i < 4; i++)
    dst[(size_t)(n0 + ty + 8 * i) * K + k0 + tx] = f2b(t[tx][ty + 8 * i]);
}

// ============ K rms-normalize (512 rows) ============
__global__ __launch_bounds__(256) void k_knorm(const ushort* __restrict__ kraw,
                                               ushort* __restrict__ kb) {
  const int row = blockIdx.x, tid = threadIdx.x;
  uint4 v = *(const uint4*)(kraw + (size_t)row * DIM + tid * 8);
  const uint32_t* vu = (const uint32_t*)&v;
  float f[8];
#pragma unroll
  for (int i = 0; i < 4; i++) {
    f[2 * i]     = b2f((ushort)(vu[i] & 0xffffu));
    f[2 * i + 1] = b2f((ushort)(vu[i] >> 16));
  }
  float s = 0.f;
#pragma unroll
  for (int i = 0; i < 8; i++) s += f[i] * f[i];
#pragma unroll
  for (int off = 32; off; off >>= 1) s += __shfl_down(s, off);
  __shared__ float wsum[4];
  __shared__ float rtot;
  if ((tid & 63) == 0) wsum[tid >> 6] = s;
  __syncthreads();
  if (tid == 0)
    rtot = rsqrtf((wsum[0] + wsum[1] + wsum[2] + wsum[3]) * (1.0f / DIM) + 1e-6f);
  __syncthreads();
  const float rms = rtot;
  ushort r[8];
#pragma unroll
  for (int i = 0; i < 8; i++) r[i] = f2b(f[i] * rms);
  *(uint4*)(kb + (size_t)row * DIM + tid * 8) = *(uint4*)r;
}

// ======================= 256x256 8-wave 4-phase GEMM (round-12 schedule) ==========
template <int OUT_MODE>
__global__ __launch_bounds__(512, 2) void k_gemm256(const ushort* __restrict__ A,
                                                    const ushort* __restrict__ Bt,
                                                    const float* __restrict__ bias,
                                                    void* __restrict__ outp,
                                                    float* __restrict__ qpart,
                                                    int M, int N, int K) {
  __shared__ __align__(16) ushort lds[65536];  // 128 KB
  const int tid = threadIdx.x;
  const int l = tid & 63, wid = tid >> 6;
  const int wm = wid >> 2, wn = wid & 3;
  const int lr = l & 15, lq = l >> 4;

  const int nwg = gridDim.x * gridDim.y;
  const int bid = blockIdx.y * gridDim.x + blockIdx.x;
  const int swz = (bid & 7) * (nwg >> 3) + (bid >> 3);
  const int m0 = (swz / gridDim.x) * 256, n0 = (swz % gridDim.x) * 256;

  f32x4_t acc[8][4];
#pragma unroll
  for (int i = 0; i < 8; i++)
#pragma unroll
    for (int j = 0; j < 4; j++) acc[i][j] = f32x4_t{0.f, 0.f, 0.f, 0.f};

  const int srow = l >> 3;
  const int schunk = ((l & 7) ^ (srow & 7)) * 8;
  auto stage = [&](int buf, int tile, int mat, int h) {
    const ushort* gp = mat ? Bt : A;
    const int rn0 = mat ? n0 : m0;
    const size_t r0 = (size_t)(rn0 + h * 128 + wid * 8 + srow);
    const ushort* g0 = gp + r0 * K + tile * 64 + schunk;
    ushort* l0 = &lds[buf * 32768 + mat * 16384 + (h * 128 + wid * 8) * 64];
    gll16(g0, l0);
    gll16(g0 + (size_t)64 * K, l0 + 64 * 64);
  };

  auto rdA = [&](int buf, int mf, int ks) -> bf16x8 {
    const int R = wm * 128 + mf * 16 + lr;
    return *(const bf16x8*)(&lds[buf * 32768 + R * 64 + (((ks * 4 + lq) ^ (R & 7)) * 8)]);
  };
  auto rdB = [&](int buf, int nf, int ks) -> bf16x8 {
    const int R = wn * 64 + nf * 16 + lr;
    return *(const bf16x8*)(&lds[buf * 32768 + 16384 + R * 64 + (((ks * 4 + lq) ^ (R & 7)) * 8)]);
  };

  const int NT = K >> 6;
  stage(0, 0, 0, 0); stage(0, 0, 0, 1); stage(0, 0, 1, 0); stage(0, 0, 1, 1);

  bf16x8 a[4][2], a2[4][2], b[2][2], b2[2][2];
  for (int kt = 0; kt < NT; kt++) {
    const int cur = kt & 1, nxt = cur ^ 1;
    const bool pf = (kt + 1 < NT);
    if (pf) { stage(nxt, kt + 1, 0, 0); asm volatile("s_waitcnt vmcnt(2)" ::: "memory"); }
    else    { asm volatile("s_waitcnt vmcnt(0)" ::: "memory"); }
    SBAR();
    __builtin_amdgcn_s_barrier();
    SBAR();
#pragma unroll
    for (int mf = 0; mf < 4; mf++) { a[mf][0] = rdA(cur, mf, 0); a[mf][1] = rdA(cur, mf, 1); }
#pragma unroll
    for (int nf = 0; nf < 2; nf++) { b[nf][0] = rdB(cur, nf, 0); b[nf][1] = rdB(cur, nf, 1); }
    __builtin_amdgcn_s_setprio(1);
#pragma unroll
    for (int mf = 0; mf < 4; mf++)
#pragma unroll
      for (int nf = 0; nf < 2; nf++) {
        acc[mf][nf] = __builtin_amdgcn_mfma_f32_16x16x32_bf16(a[mf][0], b[nf][0], acc[mf][nf], 0, 0, 0);
        acc[mf][nf] = __builtin_amdgcn_mfma_f32_16x16x32_bf16(a[mf][1], b[nf][1], acc[mf][nf], 0, 0, 0);
      }
    __builtin_amdgcn_s_setprio(0);
    SBAR();
    __builtin_amdgcn_s_barrier();
    SBAR();
#pragma unroll
    for (int mf = 0; mf < 4; mf++) { a2[mf][0] = rdA(cur, mf + 4, 0); a2[mf][1] = rdA(cur, mf + 4, 1); }
    if (pf) stage(nxt, kt + 1, 0, 1);
    SBAR();
    __builtin_amdgcn_s_barrier();
    SBAR();
    __builtin_amdgcn_s_setprio(1);
#pragma unroll
    for (int mf = 0; mf < 4; mf++)
#pragma unroll
      for (int nf = 0; nf < 2; nf++) {
        acc[mf + 4][nf] = __builtin_amdgcn_mfma_f32_16x16x32_bf16(a2[mf][0], b[nf][0], acc[mf + 4][nf], 0, 0, 0);
        acc[mf + 4][nf] = __builtin_amdgcn_mfma_f32_16x16x32_bf16(a2[mf][1], b[nf][1], acc[mf + 4][nf], 0, 0, 0);
      }
    __builtin_amdgcn_s_setprio(0);
    SBAR();
    __builtin_amdgcn_s_barrier();
    SBAR();
#pragma unroll
    for (int nf = 0; nf < 2; nf++) { b2[nf][0] = rdB(cur, nf + 2, 0); b2[nf][1] = rdB(cur, nf + 2, 1); }
    if (pf) stage(nxt, kt + 1, 1, 0);
    SBAR();
    __builtin_amdgcn_s_barrier();
    SBAR();
    __builtin_amdgcn_s_setprio(1);
#pragma unroll
    for (int mf = 0; mf < 4; mf++)
#pragma unroll
      for (int nf = 0; nf < 2; nf++) {
        acc[mf + 4][nf + 2] = __builtin_amdgcn_mfma_f32_16x16x32_bf16(a2[mf][0], b2[nf][0], acc[mf + 4][nf + 2], 0, 0, 0);
        acc[mf + 4][nf + 2] = __builtin_amdgcn_mfma_f32_16x16x32_bf16(a2[mf][1], b2[nf][1], acc[mf + 4][nf + 2], 0, 0, 0);
      }
    __builtin_amdgcn_s_setprio(0);
    SBAR();
    __builtin_amdgcn_s_barrier();
    SBAR();
#pragma unroll
    for (int mf = 0; mf < 4; mf++) { a[mf][0] = rdA(cur, mf, 0); a[mf][1] = rdA(cur, mf, 1); }
    if (pf) stage(nxt, kt + 1, 1, 1);
    SBAR();
    __builtin_amdgcn_s_barrier();
    SBAR();
    __builtin_amdgcn_s_setprio(1);
#pragma unroll
    for (int mf = 0; mf < 4; mf++)
#pragma unroll
      for (int nf = 0; nf < 2; nf++) {
        acc[mf][nf + 2] = __builtin_amdgcn_mfma_f32_16x16x32_bf16(a[mf][0], b2[nf][0], acc[mf][nf + 2], 0, 0, 0);
        acc[mf][nf + 2] = __builtin_amdgcn_mfma_f32_16x16x32_bf16(a[mf][1], b2[nf][1], acc[mf][nf + 2], 0, 0, 0);
      }
    __builtin_amdgcn_s_setprio(0);
    SBAR();
    __builtin_amdgcn_s_barrier();
    SBAR();
  }

  // ---- epilogue ----
  float bvs[4];
#pragma unroll
  for (int nf = 0; nf < 4; nf++) bvs[nf] = bias[n0 + wn * 64 + nf * 16 + lr];
#pragma unroll
  for (int nf = 0; nf < 4; nf++) {
    const int col = n0 + wn * 64 + nf * 16 + lr;
#pragma unroll
    for (int mf = 0; mf < 8; mf++) {
#pragma unroll
      for (int r = 0; r < 4; r++) {
        const int row = m0 + wm * 128 + mf * 16 + lq * 4 + r;
        const float v = acc[mf][nf][r] + bvs[nf];
        if constexpr (OUT_MODE == 0)
          ((float*)outp)[(size_t)row * N + col] = v;
        else
          ((ushort*)outp)[(size_t)row * N + col] = f2b(v);
      }
    }
  }
  if constexpr (OUT_MODE == 1) {
    const int slot = (n0 >> 8) * 4 + wn;
#pragma unroll
    for (int mf = 0; mf < 8; mf++) {
#pragma unroll
      for (int r = 0; r < 4; r++) {
        float s = 0.f;
#pragma unroll
        for (int nf = 0; nf < 4; nf++) {
          const float v = acc[mf][nf][r] + bvs[nf];
          s += v * v;
        }
        s += __shfl_xor(s, 1); s += __shfl_xor(s, 2);
        s += __shfl_xor(s, 4); s += __shfl_xor(s, 8);
        if (lr == 0)
          qpart[(size_t)(m0 + wm * 128 + mf * 16 + lq * 4 + r) * 32 + slot] = s;
      }
    }
  }
}

// ============ KV projection GEMM: M=512, N=4096, K=4096, depth-4 pipeline ============
__global__ __launch_bounds__(256) void k_gemmkv(const ushort* __restrict__ A,
                                                const ushort* __restrict__ Bt,
                                                const float* __restrict__ biasK,
                                                const float* __restrict__ biasV,
                                                ushort* __restrict__ outK,
                                                ushort* __restrict__ outVt) {
  __shared__ __align__(16) ushort As[4][128 * 32];  // 32 KB
  __shared__ __align__(16) ushort Bs[4][64 * 32];   // 16 KB
  const int tid = threadIdx.x;
  const int l = tid & 63, wid = tid >> 6;
  const int wr = wid >> 1, wc = wid & 1;
  const int lr = l & 15, lq = l >> 4;
  const int K = CTX, M = S_SEQ;

  const int bid = blockIdx.x;                 // grid = 256
  const int swz = (bid & 7) * 32 + (bid >> 3);
  const int n0 = (swz >> 2) * 64, m0 = (swz & 3) * 128;

  f32x4_t acc[4][2];
#pragma unroll
  for (int i = 0; i < 4; i++)
#pragma unroll
    for (int j = 0; j < 2; j++) acc[i][j] = f32x4_t{0.f, 0.f, 0.f, 0.f};

  const int srow = l >> 2;
  const int schunk = ((l & 3) ^ ((srow >> 1) & 3)) * 8;
  const ushort* gA = A  + (size_t)(m0 + srow) * K + schunk;
  const ushort* gB = Bt + (size_t)(n0 + wid * 16 + srow) * K + schunk;

  auto stage = [&](int buf, int kt) {
    const int ko = kt * 32;
    gll16(gA + (size_t)(wid * 16) * K + ko,      &As[buf][(wid * 16) * 32]);
    gll16(gA + (size_t)(64 + wid * 16) * K + ko, &As[buf][(64 + wid * 16) * 32]);
    gll16(gB + ko,                               &Bs[buf][(wid * 16) * 32]);
  };
  auto rdA = [&](int buf, int mi) -> bf16x8 {
    const int R = wr * 64 + mi * 16 + lr;
    return *(const bf16x8*)(&As[buf][R * 32 + ((lq ^ ((R >> 1) & 3)) * 8)]);
  };
  auto rdB = [&](int buf, int ni) -> bf16x8 {
    const int R = wc * 32 + ni * 16 + lr;
    return *(const bf16x8*)(&Bs[buf][R * 32 + ((lq ^ ((R >> 1) & 3)) * 8)]);
  };

  const int NT = K >> 5;  // 128
  stage(0, 0); stage(1, 1); stage(2, 2);
  for (int t = 0; t < NT; t++) {
    const int cur = t & 3;
    if (t + 3 < NT) { stage((t + 3) & 3, t + 3); asm volatile("s_waitcnt vmcnt(9)" ::: "memory"); }
    else if (t + 2 < NT) { asm volatile("s_waitcnt vmcnt(6)" ::: "memory"); }
    else if (t + 1 < NT) { asm volatile("s_waitcnt vmcnt(3)" ::: "memory"); }
    else                 { asm volatile("s_waitcnt vmcnt(0)" ::: "memory"); }
    SBAR();
    __builtin_amdgcn_s_barrier();
    SBAR();

    bf16x8 af[4], bfr[2];
#pragma unroll
    for (int mi = 0; mi < 4; mi++) af[mi] = rdA(cur, mi);
#pragma unroll
    for (int ni = 0; ni < 2; ni++) bfr[ni] = rdB(cur, ni);
    __builtin_amdgcn_s_setprio(1);
#pragma unroll
    for (int mi = 0; mi < 4; mi++)
#pragma unroll
      for (int ni = 0; ni < 2; ni++)
        acc[mi][ni] = __builtin_amdgcn_mfma_f32_16x16x32_bf16(af[mi], bfr[ni], acc[mi][ni], 0, 0, 0);
    __builtin_amdgcn_s_setprio(0);
    SBAR();
    __builtin_amdgcn_s_barrier();
    SBAR();
  }

  if (n0 < DIM) {
#pragma unroll
    for (int mi = 0; mi < 4; mi++) {
#pragma unroll
      for (int ni = 0; ni < 2; ni++) {
        const int col = n0 + wc * 32 + ni * 16 + lr;
        const float bv = biasK[col];
#pragma unroll
        for (int r = 0; r < 4; r++) {
          const int row = m0 + wr * 64 + mi * 16 + lq * 4 + r;
          outK[(size_t)row * DIM + col] = f2b(acc[mi][ni][r] + bv);
        }
      }
    }
  } else {
    // V block: transpose through LDS for coalesced V^T stores
    ushort* ldst = &As[0][0];
    __syncthreads();
#pragma unroll
    for (int mi = 0; mi < 4; mi++) {
#pragma unroll
      for (int ni = 0; ni < 2; ni++) {
        const int ccol = wc * 32 + ni * 16 + lr;
        const float bv = biasV[n0 - DIM + ccol];
#pragma unroll
        for (int r = 0; r < 4; r++) {
          const int crow = wr * 64 + mi * 16 + lq * 4 + r;
          ldst[ccol * 128 + crow] = f2b(acc[mi][ni][r] + bv);
        }
      }
    }
    __syncthreads();
    const int c = tid >> 2, j0 = (tid & 3) * 32;
    ushort* dst = outVt + (size_t)(n0 - DIM + c) * M + m0 + j0;
#pragma unroll
    for (int k2 = 0; k2 < 4; k2++)
      *(uint4*)(dst + k2 * 8) = *(const uint4*)(ldst + c * 128 + j0 + k2 * 8);
  }
}

// ============ Flash attention, swapped-operand 32x32x16, register-diet softmax ============
// p[32] eliminated: max/exp/pack operate directly on sA/sB (same value mapping:
// c[0..7] <- sA pairs, c[8..15] <- sB pairs), shortening live ranges.
__global__ __launch_bounds__(256) void k_attn(const ushort* __restrict__ Qraw,
                                              const ushort* __restrict__ Kb,
                                              const ushort* __restrict__ Vt,
                                              const float* __restrict__ qpart,
                                              const float* __restrict__ g2,
                                              ushort* __restrict__ Ob) {
  __shared__ __align__(16) ushort smem[16384];  // 32KB: Ks [64][128] + Vs [128][64]
  ushort* Ks = smem;
  ushort* Vs = smem + 64 * 128;

  const int tid = threadIdx.x;
  const int l = tid & 63, wid = tid >> 6;
  const int lo = l & 31, hi = l >> 5;

  const int bid = blockIdx.x;                  // grid = 1024
  const int swz = (bid & 7) * 128 + (bid >> 3);
  const int h = swz >> 6;
  const int q0 = (swz & 63) * 128 + wid * 32;

  bf16x8 qf[8];
  {
    float ssum = 0.f;
    const float* pp = qpart + (size_t)(q0 + lo) * 32;
#pragma unroll
    for (int i = 0; i < 8; i++) {
      float4 t = *(const float4*)(pp + i * 4);
      ssum += t.x + t.y + t.z + t.w;
    }
    const float qs = rsqrtf(ssum * (1.0f / DIM) + 1e-6f);
    const ushort* qp = Qraw + (size_t)(q0 + lo) * DIM + h * HD + hi * 8;
    const float* gp = g2 + h * HD + hi * 8;
#pragma unroll
    for (int ds = 0; ds < 8; ds++) {
      union { uint4 u; ushort us[8]; } rw;
      rw.u = *(const uint4*)(qp + ds * 16);
      float4 ga_ = *(const float4*)(gp + ds * 16);
      float4 gb_ = *(const float4*)(gp + ds * 16 + 4);
      union { uint32_t w[4]; bf16x8 v; } ov;
      ov.w[0] = pk2(b2f(rw.us[0]) * qs * ga_.x, b2f(rw.us[1]) * qs * ga_.y);
      ov.w[1] = pk2(b2f(rw.us[2]) * qs * ga_.z, b2f(rw.us[3]) * qs * ga_.w);
      ov.w[2] = pk2(b2f(rw.us[4]) * qs * gb_.x, b2f(rw.us[5]) * qs * gb_.y);
      ov.w[3] = pk2(b2f(rw.us[6]) * qs * gb_.z, b2f(rw.us[7]) * qs * gb_.w);
      qf[ds] = ov.v;
    }
  }

  f32x16_t o[4] = {};          // O^T: lane q = lo, d = nt*32 + crow(r,hi)
  float m_run = -1e30f, l_run = 0.f;

  for (int kvb = 0; kvb < S_SEQ / 64; kvb++) {
    __syncthreads();
#pragma unroll
    for (int i = 0; i < 4; i++) {
      const int c = i * 256 + tid, row = c >> 4, cs = c & 15;
      gll16(Kb + (size_t)(kvb * 64 + row) * DIM + h * HD + ((cs ^ (row & 7)) * 8),
            Ks + c * 8);
    }
#pragma unroll
    for (int i = 0; i < 4; i++) {
      const int c = i * 256 + tid, row = c >> 3, cs = c & 7;
      gll16(Vt + (size_t)(h * HD + row) * S_SEQ + kvb * 64 + ((cs ^ (row & 7)) * 8),
            Vs + c * 8);
    }
    __syncthreads();

    f32x16_t sA = {}, sB = {};
#pragma unroll
    for (int ds = 0; ds < 8; ds++) {
      const int ch = ((hi + ds * 2) ^ (lo & 7)) * 8;
      bf16x8 kA = *(const bf16x8*)(Ks + lo * 128 + ch);
      bf16x8 kB = *(const bf16x8*)(Ks + (32 + lo) * 128 + ch);
      sA = __builtin_amdgcn_mfma_f32_32x32x16_bf16(kA, qf[ds], sA, 0, 0, 0);
      sB = __builtin_amdgcn_mfma_f32_32x32x16_bf16(kB, qf[ds], sB, 0, 0, 0);
    }

    // ---- online softmax directly on sA/sB (no p[] copy) ----
    float pm = sA[0];
#pragma unroll
    for (int i = 1; i < 16; i++) pm = fmaxf(pm, sA[i]);
#pragma unroll
    for (int i = 0; i < 16; i++) pm = fmaxf(pm, sB[i]);
    pm = fmaxf(pm, __shfl_xor(pm, 32));
    const float mn = fmaxf(m_run, pm);
    const float corr = __expf(m_run - mn);
    m_run = mn;
    float ps = 0.f;
    uint32_t c[16];
#pragma unroll
    for (int j = 0; j < 8; j++) {
      const float e0 = __expf(sA[2 * j] - mn);
      const float e1 = __expf(sA[2 * j + 1] - mn);
      ps += e0 + e1;
      c[j] = pk2(e0, e1);
    }
#pragma unroll
    for (int j = 0; j < 8; j++) {
      const float e0 = __expf(sB[2 * j] - mn);
      const float e1 = __expf(sB[2 * j + 1] - mn);
      ps += e0 + e1;
      c[8 + j] = pk2(e0, e1);
    }
    ps += __shfl_xor(ps, 32);
    l_run = l_run * corr + ps;
#pragma unroll
    for (int nt = 0; nt < 4; nt++) o[nt] *= corr;

    bf16x8 pf[4];
#pragma unroll
    for (int s = 0; s < 4; s++) {
      const uint32_t ca = c[4 * s], cb = c[4 * s + 1], cc = c[4 * s + 2], cd = c[4 * s + 3];
      const uint32_t sa = __shfl_xor(ca, 32), sb = __shfl_xor(cb, 32);
      const uint32_t sc = __shfl_xor(cc, 32), sd = __shfl_xor(cd, 32);
      union { uint32_t u[4]; bf16x8 v; } f;
      f.u[0] = hi ? sc : ca; f.u[1] = hi ? sd : cb;
      f.u[2] = hi ? cc : sa; f.u[3] = hi ? cd : sb;
      pf[s] = f.v;
    }

#pragma unroll
    for (int nt = 0; nt < 4; nt++) {
      const int vrow = nt * 32 + lo;
#pragma unroll
      for (int s = 0; s < 4; s++) {
        bf16x8 vf = *(const bf16x8*)(Vs + vrow * 64 + (((s * 2 + hi) ^ (lo & 7)) * 8));
        o[nt] = __builtin_amdgcn_mfma_f32_32x32x16_bf16(vf, pf[s], o[nt], 0, 0, 0);
      }
    }
  }

  const float inv = 1.0f / l_run;
#pragma unroll
  for (int nt = 0; nt < 4; nt++) o[nt] *= inv;

  __syncthreads();
  float* tb = (float*)smem + wid * (32 * 33);
  const int q2 = l >> 1, dh = (l & 1) * 16;
#pragma unroll
  for (int nt = 0; nt < 4; nt++) {
#pragma unroll
    for (int r = 0; r < 16; r++)
      tb[lo * 33 + ((r & 3) + 8 * (r >> 2) + 4 * hi)] = o[nt][r];
    asm volatile("s_waitcnt lgkmcnt(0)" ::: "memory");
    SBAR();
    ushort tmp[16];
#pragma unroll
    for (int j = 0; j < 16; j++) tmp[j] = f2b(tb[q2 * 33 + dh + j]);
    asm volatile("s_waitcnt lgkmcnt(0)" ::: "memory");
    SBAR();
    const size_t oaddr = (size_t)(q0 + q2) * DIM + h * HD + nt * 32 + dh;
    *(uint4*)(Ob + oaddr) = *(uint4*)tmp;
    *(uint4*)(Ob + oaddr + 8) = *(uint4*)(tmp + 8);
  }
}

extern "C" void kernel_launch(void* const* d_in, const int* in_sizes, int n_in,
                              void* d_out, int out_size, void* d_ws, size_t ws_size,
                              hipStream_t stream) {
  const float* x   = (const float*)d_in[0];
  const float* ctx = (const float*)d_in[1];
  const float* Wq  = (const float*)d_in[2];
  const float* bq  = (const float*)d_in[3];
  const float* Wk  = (const float*)d_in[4];
  const float* bk  = (const float*)d_in[5];
  const float* Wv  = (const float*)d_in[6];
  const float* bv  = (const float*)d_in[7];
  const float* Wo  = (const float*)d_in[8];
  const float* bo  = (const float*)d_in[9];
  const float* gq  = (const float*)d_in[10];
  const float* gk  = (const float*)d_in[11];

  char* ws = (char*)d_ws;
  ushort* wqt    = (ushort*)(ws);                 // [2048][2048] bf16   8.39MB
  ushort* wkt    = (ushort*)(ws + 8388608);       // [2048][4096] bf16  16.78MB } adjacent =>
  ushort* wvt    = (ushort*)(ws + 25165824);      // [2048][4096] bf16  16.78MB } [4096][4096] KV
  ushort* wot    = (ushort*)(ws + 41943040);      // [2048][2048] bf16   8.39MB
  ushort* ctxb   = (ushort*)(ws + 50331648);      // [512][4096]  bf16   4.19MB
  float*  g2     = (float*)(ws + 54558720);       // [2048] f32   8KB
  float*  qpart  = (float*)(ws + 56623104);       // [8192][32] f32  1MB
  ushort* kb     = (ushort*)(ws + 83886080);      // [512][2048]  bf16   2.10MB
  ushort* vt     = (ushort*)(ws + 85983232);      // [2048][512]  bf16   2.10MB
  ushort* xb     = (ushort*)(ws + 88080384);      // [8192][2048] bf16  33.55MB
  ushort* kraw   = (ushort*)(ws + 88080384);      // aliases xb (dead after Qproj)
  ushort* attnb  = (ushort*)(ws + 88080384);      // aliases (kraw dead after knorm)
  ushort* qraw   = (ushort*)(ws + 121634816);     // [8192][2048] bf16  33.55MB

  // 1. preprocessing: casts + weight transposes + G
  k_prep<<<33793, 256, 0, stream>>>(x, ctx, Wq, Wk, Wv, Wo, gq, gk,
                                    xb, ctxb, wqt, wkt, wvt, wot, g2);
  // 2. Q projection: qraw = x@Wq + bq (bf16) + per-row sumsq partials -> qpart
  k_gemm256<1><<<dim3(DIM / 256, L_SEQ / 256), 512, 0, stream>>>(xb, wqt, bq, qraw, qpart, L_SEQ, DIM, DIM);
  // 3. fused K+V projection (depth-4 pipeline)
  k_gemmkv<<<256, 256, 0, stream>>>(ctxb, wkt, bk, bv, kraw, vt);
  // 4. K rms-normalize
  k_knorm<<<S_SEQ, 256, 0, stream>>>(kraw, kb);
  // 5. attention (register-diet softmax)
  k_attn<<<L_SEQ / 128 * NH, 256, 0, stream>>>(qraw, kb, vt, qpart, g2, attnb);
  // 6. out = attn @ Wo + bo (fp32)
  k_gemm256<0><<<dim3(DIM / 256, L_SEQ / 256), 512, 0, stream>>>(attnb, wot, bo, d_out, nullptr, L_SEQ, DIM, DIM);
}